// Round 3
// baseline (37814.755 us; speedup 1.0000x reference)
//
#include <hip/hip_runtime.h>
#include <hip/hip_bf16.h>

using bf16 = __hip_bfloat16;
typedef short bf16x8_t __attribute__((ext_vector_type(8)));   // 8 bf16 (4 VGPRs)
typedef float f32x4_t __attribute__((ext_vector_type(4)));

// sizes
#define Bsz 32
#define Ssz 128
#define Tsz 128
#define Esz 256
#define Hsz 512
#define VTsz 16000
#define GBLK 128   // blocks in each persistent kernel (all co-resident on 256 CUs)

__device__ inline float sigm(float x)      { return 1.f / (1.f + __expf(-x)); }
__device__ inline float tanh_fast(float x) { return 1.f - 2.f / (1.f + __expf(2.f * x)); }
__device__ inline float dot4(float4 a, float4 b) {
  return a.x*b.x + a.y*b.y + a.z*b.z + a.w*b.w;
}
__device__ inline void cvt8(uint4 u, float* f) {   // 8 packed bf16 -> 8 f32
  f[0]=__uint_as_float(u.x<<16); f[1]=__uint_as_float(u.x&0xffff0000u);
  f[2]=__uint_as_float(u.y<<16); f[3]=__uint_as_float(u.y&0xffff0000u);
  f[4]=__uint_as_float(u.z<<16); f[5]=__uint_as_float(u.z&0xffff0000u);
  f[6]=__uint_as_float(u.w<<16); f[7]=__uint_as_float(u.w&0xffff0000u);
}

// Sense-free generation barrier. bar[0]=count, bar[16]=generation (separate lines).
__device__ inline void grid_barrier(int* cnt, int* gen) {
  __threadfence();                       // release this thread's writes (device scope)
  __syncthreads();
  if (threadIdx.x == 0) {
    int g = __hip_atomic_load(gen, __ATOMIC_SEQ_CST, __HIP_MEMORY_SCOPE_AGENT);
    int a = __hip_atomic_fetch_add(cnt, 1, __ATOMIC_SEQ_CST, __HIP_MEMORY_SCOPE_AGENT);
    if (a == GBLK - 1) {
      __hip_atomic_store(cnt, 0, __ATOMIC_SEQ_CST, __HIP_MEMORY_SCOPE_AGENT);
      __hip_atomic_fetch_add(gen, 1, __ATOMIC_SEQ_CST, __HIP_MEMORY_SCOPE_AGENT);
    } else {
      while (__hip_atomic_load(gen, __ATOMIC_SEQ_CST, __HIP_MEMORY_SCOPE_AGENT) == g)
        __builtin_amdgcn_s_sleep(1);
    }
  }
  __syncthreads();
  __threadfence();                       // acquire: see other blocks' writes
}

// ---------------------------------------------------------------------------
// init: zero h0 and the barrier words (ws is poisoned 0xAA before every launch)
// ---------------------------------------------------------------------------
__global__ __launch_bounds__(256) void init_state(float* __restrict__ hbuf,
                                                  int* __restrict__ bar) {
  int idx = blockIdx.x * 256 + threadIdx.x;
  if (idx < Bsz * Hsz) hbuf[idx] = 0.f;
  if (idx < 32) bar[idx] = 0;
}

// ---------------------------------------------------------------------------
// Embedding gather + f32->bf16 pack. One thread per 8-elem chunk.
// ---------------------------------------------------------------------------
__global__ __launch_bounds__(256) void embed_gather(
    const int* __restrict__ src, const int* __restrict__ tgt,
    const float* __restrict__ es, const float* __restrict__ et,
    bf16* __restrict__ xs_b, bf16* __restrict__ ys_b)
{
  int idx = blockIdx.x * 256 + threadIdx.x;     // 0 .. 262143
  int which = idx >> 17;
  int c = idx & 131071;
  int row = c >> 5, cc = c & 31;
  const float* srcp; bf16* dstp;
  if (which == 0) { srcp = es + (size_t)src[row] * Esz; dstp = xs_b + (size_t)row * Esz; }
  else            { srcp = et + (size_t)tgt[row] * Esz; dstp = ys_b + (size_t)row * Esz; }
  float f[8]; const float4* s4 = (const float4*)(srcp + cc * 8);
  float4 a = s4[0], b = s4[1];
  f[0]=a.x; f[1]=a.y; f[2]=a.z; f[3]=a.w; f[4]=b.x; f[5]=b.y; f[6]=b.z; f[7]=b.w;
  uint4 r;
  auto pk=[&](float x,float y){
    unsigned short lo=__builtin_bit_cast(unsigned short,__float2bfloat16(x));
    unsigned short hi=__builtin_bit_cast(unsigned short,__float2bfloat16(y));
    return (unsigned)lo | ((unsigned)hi<<16); };
  r.x=pk(f[0],f[1]); r.y=pk(f[2],f[3]); r.z=pk(f[4],f[5]); r.w=pk(f[6],f[7]);
  *(uint4*)(dstp + cc * 8) = r;
}

// ---------------------------------------------------------------------------
// Pack GEMM B-operands f32 -> bf16 (row-major): encWih_b(1536x256),
// decWihY_b(1536x256 from ld768), attnWe_b(512x512 from attn_W[:,512:]),
// fcW_b(16000x512). total 9240576 = 36096*256 threads.
// ---------------------------------------------------------------------------
__global__ __launch_bounds__(256) void pack_weights(
    const float* __restrict__ enc_Wih, const float* __restrict__ dec_Wih,
    const float* __restrict__ attn_W,  const float* __restrict__ fc_W,
    bf16* __restrict__ encWih_b, bf16* __restrict__ decWihY_b,
    bf16* __restrict__ attnWe_b, bf16* __restrict__ fcW_b)
{
  int idx = blockIdx.x * 256 + threadIdx.x;
  const int R1 = 1536 * 256, R2 = 1536 * 256, R3 = 512 * 512;
  if (idx < R1) {
    encWih_b[idx] = __float2bfloat16(enc_Wih[idx]);
  } else if (idx < R1 + R2) {
    int r = idx - R1, row = r >> 8, col = r & 255;
    decWihY_b[r] = __float2bfloat16(dec_Wih[(size_t)row * 768 + col]);
  } else if (idx < R1 + R2 + R3) {
    int r = idx - R1 - R2, row = r >> 9, col = r & 511;
    attnWe_b[r] = __float2bfloat16(attn_W[(size_t)row * 1024 + 512 + col]);
  } else {
    int r = idx - R1 - R2 - R3;
    fcW_b[r] = __float2bfloat16(fc_W[r]);
  }
}

// ---------------------------------------------------------------------------
// MFMA GEMM: C[m,n] = sum_k A[m,k]*B[n,k] + bias[n]; A,B bf16 row-major.
// 128x128 tile, BK=64, 256 thr = 4 waves (2x2 of 64x64), 16x16x32 MFMA.
// ---------------------------------------------------------------------------
__device__ inline void store_c(float* p, float v) { *p = v; }
__device__ inline void store_c(bf16*  p, float v) { *p = __float2bfloat16(v); }

template <typename CT>
__global__ __launch_bounds__(256) void gemm_bt(
    const bf16* __restrict__ A, int lda,
    const bf16* __restrict__ B, int ldb,
    CT* __restrict__ C, int ldc,
    const float* __restrict__ bias, int K)
{
  __shared__ __align__(16) bf16 As[128 * 64];
  __shared__ __align__(16) bf16 Bs[128 * 64];
  const int tid = threadIdx.x;
  const int m0 = blockIdx.y * 128, n0 = blockIdx.x * 128;
  const int lane = tid & 63, wave = tid >> 6;
  const int wm = (wave >> 1) * 64, wn = (wave & 1) * 64;
  const int fr = lane & 15, quad = lane >> 4;

  f32x4_t acc[4][4];
  const f32x4_t zero = {0.f, 0.f, 0.f, 0.f};
#pragma unroll
  for (int i = 0; i < 4; ++i)
#pragma unroll
    for (int j = 0; j < 4; ++j) acc[i][j] = zero;

  for (int k0 = 0; k0 < K; k0 += 64) {
    __syncthreads();
#pragma unroll
    for (int j = 0; j < 4; ++j) {
      int c = j * 256 + tid;
      int row = c >> 3, cc = c & 7;
      *(uint4*)(As + row * 64 + cc * 8) =
          *(const uint4*)(A + (size_t)(m0 + row) * lda + k0 + cc * 8);
      *(uint4*)(Bs + row * 64 + cc * 8) =
          *(const uint4*)(B + (size_t)(n0 + row) * ldb + k0 + cc * 8);
    }
    __syncthreads();
#pragma unroll
    for (int kk = 0; kk < 64; kk += 32) {
      bf16x8_t af[4], bfr[4];
#pragma unroll
      for (int mt = 0; mt < 4; ++mt)
        af[mt] = *(const bf16x8_t*)(As + (wm + mt * 16 + fr) * 64 + kk + quad * 8);
#pragma unroll
      for (int nt = 0; nt < 4; ++nt)
        bfr[nt] = *(const bf16x8_t*)(Bs + (wn + nt * 16 + fr) * 64 + kk + quad * 8);
#pragma unroll
      for (int mt = 0; mt < 4; ++mt)
#pragma unroll
        for (int nt = 0; nt < 4; ++nt)
          acc[mt][nt] = __builtin_amdgcn_mfma_f32_16x16x32_bf16(
              af[mt], bfr[nt], acc[mt][nt], 0, 0, 0);
    }
  }

#pragma unroll
  for (int mt = 0; mt < 4; ++mt) {
#pragma unroll
    for (int nt = 0; nt < 4; ++nt) {
      int n = n0 + wn + nt * 16 + fr;
      float bv = bias[n];
#pragma unroll
      for (int r = 0; r < 4; ++r) {
        int m = m0 + wm + mt * 16 + quad * 4 + r;
        store_c(&C[(size_t)m * ldc + n], acc[mt][nt][r] + bv);
      }
    }
  }
}

// ---------------------------------------------------------------------------
// Persistent encoder: 128 blocks x 512 thr, 1 grid barrier / step.
// Block g owns i = g*4 .. g*4+3. Thread = (b, il, kq): kq = k-quarter of 128.
// W rows read directly from the f32 input (j-major, L1-resident: 4*3 rows).
// ---------------------------------------------------------------------------
__global__ __launch_bounds__(512) void enc_persist(
    const float* __restrict__ enc_gi, const float* __restrict__ Whh,
    const float* __restrict__ bhh, float* __restrict__ hbuf,
    bf16* __restrict__ enc_out_b, int* __restrict__ bar)
{
  const int g = blockIdx.x, tid = threadIdx.x;
  const int o = tid >> 2, kq = tid & 3;
  const int b = o >> 2, il = o & 3;
  const int i = g * 4 + il, k0 = kq * 128;
  const float4* wr = (const float4*)(Whh + (size_t)i * 512 + k0);
  const float4* wz = (const float4*)(Whh + (size_t)(512 + i) * 512 + k0);
  const float4* wn = (const float4*)(Whh + (size_t)(1024 + i) * 512 + k0);
  const float br = bhh[i], bz = bhh[512 + i], bn = bhh[1024 + i];

  for (int t = 0; t < Ssz; ++t) {
    const int cur = t & 1;
    const float4* h4 = (const float4*)(hbuf + cur * (Bsz * Hsz) + b * Hsz + k0);
    float sr = 0.f, sz = 0.f, sn = 0.f;
#pragma unroll 8
    for (int c = 0; c < 32; ++c) {
      float4 h = h4[c];
      sr += dot4(h, wr[c]); sz += dot4(h, wz[c]); sn += dot4(h, wn[c]);
    }
    sr += __shfl_xor(sr, 1); sr += __shfl_xor(sr, 2);
    sz += __shfl_xor(sz, 1); sz += __shfl_xor(sz, 2);
    sn += __shfl_xor(sn, 1); sn += __shfl_xor(sn, 2);
    if (kq == 0) {
      const float* gi = enc_gi + ((size_t)(b * Ssz) + t) * 1536;
      float r   = sigm(gi[i] + sr + br);
      float z   = sigm(gi[512 + i] + sz + bz);
      float ghn = sn + bn;
      float n   = tanh_fast(gi[1024 + i] + r * ghn);
      float hp  = hbuf[cur * (Bsz * Hsz) + b * Hsz + i];
      float h2  = (1.f - z) * n + z * hp;
      hbuf[(cur ^ 1) * (Bsz * Hsz) + b * Hsz + i] = h2;
      enc_out_b[((size_t)(b * Ssz) + t) * Hsz + i] = __float2bfloat16(h2);
    }
    grid_barrier(bar, bar + 16);
  }
}

// ---------------------------------------------------------------------------
// Persistent decoder: 128 blocks x 512 thr, 3 grid barriers / step.
// A: gh = h@Whh^T + bhh (i-split) and hW = h@Wh^T (same i-split; Wh rows are
//    attn_W[j][0:512], stride 1024).  B: blocks 0..31 (one per batch) do
//    scores -> softmax -> ctx from bf16 enc_proj/enc_out.  C: ctx@WihC^T
//    (rows dec_Wih[j][256:768], stride 768) + gates -> h2, dec_out bf16.
// ---------------------------------------------------------------------------
__global__ __launch_bounds__(512) void dec_persist(
    const float* __restrict__ dec_gi_y, const float* __restrict__ Whh,
    const float* __restrict__ attn_W,   const float* __restrict__ dec_Wih,
    const float* __restrict__ bhh,      const float* __restrict__ attn_v,
    const bf16* __restrict__ enc_proj_b, const bf16* __restrict__ enc_out_b,
    float* __restrict__ hbuf, float* __restrict__ gh_ws,
    float* __restrict__ hW_ws, float* __restrict__ ctx_ws,
    bf16* __restrict__ dec_out_b, int* __restrict__ bar)
{
  __shared__ float s_hw[512], s_vv[512], s_sc[128], s_red[2], s_red2[2], s_inv;
  __shared__ float s_ps[8][64][8];

  const int g = blockIdx.x, tid = threadIdx.x;
  const int o = tid >> 2, kq = tid & 3;
  const int b = o >> 2, il = o & 3;
  const int i = g * 4 + il, k0 = kq * 128;

  const float4* ar = (const float4*)(Whh + (size_t)i * 512 + k0);
  const float4* az = (const float4*)(Whh + (size_t)(512 + i) * 512 + k0);
  const float4* an = (const float4*)(Whh + (size_t)(1024 + i) * 512 + k0);
  const float4* aw = (const float4*)(attn_W + (size_t)i * 1024 + k0);
  const float4* cr = (const float4*)(dec_Wih + (size_t)i * 768 + 256 + k0);
  const float4* cz = (const float4*)(dec_Wih + (size_t)(512 + i) * 768 + 256 + k0);
  const float4* cn = (const float4*)(dec_Wih + (size_t)(1024 + i) * 768 + 256 + k0);
  const float br = bhh[i], bz = bhh[512 + i], bn = bhh[1024 + i];

  if (g < Bsz) s_vv[tid] = attn_v[tid];   // tid < 512 exactly

  for (int t = 0; t < Tsz; ++t) {
    const int cur = t & 1;
    // ---- Phase A -----------------------------------------------------------
    {
      const float4* h4 = (const float4*)(hbuf + cur * (Bsz * Hsz) + b * Hsz + k0);
      float sr = 0.f, sz = 0.f, sn = 0.f, sw = 0.f;
#pragma unroll 4
      for (int c = 0; c < 32; ++c) {
        float4 h = h4[c];
        sr += dot4(h, ar[c]); sz += dot4(h, az[c]);
        sn += dot4(h, an[c]); sw += dot4(h, aw[c]);
      }
      sr += __shfl_xor(sr, 1); sr += __shfl_xor(sr, 2);
      sz += __shfl_xor(sz, 1); sz += __shfl_xor(sz, 2);
      sn += __shfl_xor(sn, 1); sn += __shfl_xor(sn, 2);
      sw += __shfl_xor(sw, 1); sw += __shfl_xor(sw, 2);
      if (kq == 0) {
        gh_ws[b * 1536 + i]        = sr + br;
        gh_ws[b * 1536 + 512 + i]  = sz + bz;
        gh_ws[b * 1536 + 1024 + i] = sn + bn;
        hW_ws[b * Hsz + i] = sw;
      }
    }
    grid_barrier(bar, bar + 16);
    // ---- Phase B (blocks 0..31; one batch each) ----------------------------
    if (g < Bsz) {
      const int bb = g;
      s_hw[tid] = hW_ws[bb * Hsz + tid];
      __syncthreads();
      const int wv = tid >> 6, ln = tid & 63;
      for (int s = wv; s < Ssz; s += 8) {
        uint4 u = *(const uint4*)(enc_proj_b + ((size_t)(bb * Ssz) + s) * Hsz + ln * 8);
        float f[8]; cvt8(u, f);
        float pp = 0.f;
#pragma unroll
        for (int e = 0; e < 8; ++e) {
          int ii = ln * 8 + e;
          pp += tanh_fast(s_hw[ii] + f[e]) * s_vv[ii];
        }
#pragma unroll
        for (int off = 32; off; off >>= 1) pp += __shfl_down(pp, off);
        if (ln == 0) s_sc[s] = pp;
      }
      __syncthreads();
      if (tid < 128) {
        float v = s_sc[tid];
#pragma unroll
        for (int off = 32; off; off >>= 1) v = fmaxf(v, __shfl_down(v, off));
        if ((tid & 63) == 0) s_red[tid >> 6] = v;
      }
      __syncthreads();
      float mx = fmaxf(s_red[0], s_red[1]);
      if (tid < 128) {
        float e = __expf(s_sc[tid] - mx);
        s_sc[tid] = e;
        float v = e;
#pragma unroll
        for (int off = 32; off; off >>= 1) v += __shfl_down(v, off);
        if ((tid & 63) == 0) s_red2[tid >> 6] = v;
      }
      __syncthreads();
      if (tid == 0) s_inv = 1.f / (s_red2[0] + s_red2[1]);
      __syncthreads();
      const int sg = tid >> 6, cc = tid & 63;
      float acc[8] = {0,0,0,0,0,0,0,0};
      for (int s = sg * 16; s < sg * 16 + 16; ++s) {
        float wsc = s_sc[s];
        uint4 u = *(const uint4*)(enc_out_b + ((size_t)(bb * Ssz) + s) * Hsz + cc * 8);
        float f[8]; cvt8(u, f);
#pragma unroll
        for (int e = 0; e < 8; ++e) acc[e] += wsc * f[e];
      }
#pragma unroll
      for (int e = 0; e < 8; ++e) s_ps[sg][cc][e] = acc[e];
      __syncthreads();
      if (tid < 64) {
        float inv = s_inv;
#pragma unroll
        for (int e = 0; e < 8; ++e) {
          float s2 = 0.f;
#pragma unroll
          for (int q = 0; q < 8; ++q) s2 += s_ps[q][tid][e];
          ctx_ws[bb * Hsz + tid * 8 + e] = s2 * inv;
        }
      }
    }
    grid_barrier(bar, bar + 16);
    // ---- Phase C -----------------------------------------------------------
    {
      const float4* c4 = (const float4*)(ctx_ws + b * Hsz + k0);
      float tr = 0.f, tz = 0.f, tn = 0.f;
#pragma unroll 8
      for (int c = 0; c < 32; ++c) {
        float4 cx = c4[c];
        tr += dot4(cx, cr[c]); tz += dot4(cx, cz[c]); tn += dot4(cx, cn[c]);
      }
      tr += __shfl_xor(tr, 1); tr += __shfl_xor(tr, 2);
      tz += __shfl_xor(tz, 1); tz += __shfl_xor(tz, 2);
      tn += __shfl_xor(tn, 1); tn += __shfl_xor(tn, 2);
      if (kq == 0) {
        const float* giy = dec_gi_y + ((size_t)(b * Tsz) + t) * 1536;
        float ghr = gh_ws[b * 1536 + i];
        float ghz = gh_ws[b * 1536 + 512 + i];
        float ghn = gh_ws[b * 1536 + 1024 + i];
        float r = sigm(giy[i] + tr + ghr);
        float z = sigm(giy[512 + i] + tz + ghz);
        float n = tanh_fast(giy[1024 + i] + tn + r * ghn);
        float hp = hbuf[cur * (Bsz * Hsz) + b * Hsz + i];
        float h2 = (1.f - z) * n + z * hp;
        hbuf[(cur ^ 1) * (Bsz * Hsz) + b * Hsz + i] = h2;
        dec_out_b[((size_t)(b * Tsz) + t) * Hsz + i] = __float2bfloat16(h2);
      }
    }
    grid_barrier(bar, bar + 16);
  }
}

// ---------------------------------------------------------------------------
extern "C" void kernel_launch(void* const* d_in, const int* in_sizes, int n_in,
                              void* d_out, int out_size, void* d_ws, size_t ws_size,
                              hipStream_t stream) {
  const int*   src      = (const int*)d_in[0];
  const int*   tgt      = (const int*)d_in[1];
  const float* emb_src  = (const float*)d_in[2];
  const float* emb_tgt  = (const float*)d_in[3];
  const float* enc_Wih  = (const float*)d_in[4];
  const float* enc_Whh  = (const float*)d_in[5];
  const float* enc_bih  = (const float*)d_in[6];
  const float* enc_bhh  = (const float*)d_in[7];
  const float* dec_Wih  = (const float*)d_in[8];
  const float* dec_Whh  = (const float*)d_in[9];
  const float* dec_bih  = (const float*)d_in[10];
  const float* dec_bhh  = (const float*)d_in[11];
  const float* attn_W   = (const float*)d_in[12];
  const float* attn_b   = (const float*)d_in[13];
  const float* attn_v   = (const float*)d_in[14];
  const float* fc_W     = (const float*)d_in[15];
  const float* fc_b     = (const float*)d_in[16];
  float* out = (float*)d_out;

  char* p = (char*)d_ws;
  auto alloc = [&](size_t n) { char* r = p; p += (n + 255) & ~(size_t)255; return r; };
  float* enc_gi     = (float*)alloc(4096ull * 1536 * 4);
  float* dec_gi_y   = (float*)alloc(4096ull * 1536 * 4);
  bf16*  enc_out_b  = (bf16*)alloc(4096ull * 512 * 2);
  bf16*  enc_proj_b = (bf16*)alloc(4096ull * 512 * 2);
  bf16*  dec_out_b  = (bf16*)alloc(4096ull * 512 * 2);
  bf16*  xs_b       = (bf16*)alloc(4096ull * 256 * 2);
  bf16*  ys_b       = (bf16*)alloc(4096ull * 256 * 2);
  bf16*  encWih_b   = (bf16*)alloc(1536ull * 256 * 2);
  bf16*  decWihY_b  = (bf16*)alloc(1536ull * 256 * 2);
  bf16*  attnWe_b   = (bf16*)alloc(512ull * 512 * 2);
  bf16*  fcW_b      = (bf16*)alloc(16000ull * 512 * 2);
  float* hbuf       = (float*)alloc(2ull * Bsz * Hsz * 4);
  float* gh_ws      = (float*)alloc((size_t)Bsz * 1536 * 4);
  float* hW_ws      = (float*)alloc((size_t)Bsz * Hsz * 4);
  float* ctx_ws     = (float*)alloc((size_t)Bsz * Hsz * 4);
  int*   bar        = (int*)alloc(64 * 4);

  embed_gather<<<1024, 256, 0, stream>>>(src, tgt, emb_src, emb_tgt, xs_b, ys_b);
  pack_weights<<<36096, 256, 0, stream>>>(enc_Wih, dec_Wih, attn_W, fc_W,
                                          encWih_b, decWihY_b, attnWe_b, fcW_b);

  // enc_gi = xs @ enc_Wih^T + bih   (M=4096, N=1536, K=256)
  gemm_bt<float><<<dim3(12, 32), 256, 0, stream>>>(xs_b, 256, encWih_b, 256,
                                                   enc_gi, 1536, enc_bih, 256);
  // dec_gi_y = ys @ dec_Wih[:, :E]^T + bih
  gemm_bt<float><<<dim3(12, 32), 256, 0, stream>>>(ys_b, 256, decWihY_b, 256,
                                                   dec_gi_y, 1536, dec_bih, 256);

  init_state<<<64, 256, 0, stream>>>(hbuf, bar);
  enc_persist<<<GBLK, 512, 0, stream>>>(enc_gi, enc_Whh, enc_bhh, hbuf,
                                        enc_out_b, bar);

  // enc_proj = enc_out @ We^T + attn_b  (M=4096, N=512, K=512) -> bf16
  gemm_bt<bf16><<<dim3(4, 32), 256, 0, stream>>>(enc_out_b, 512, attnWe_b, 512,
                                                 enc_proj_b, 512, attn_b, 512);

  dec_persist<<<GBLK, 512, 0, stream>>>(dec_gi_y, dec_Whh, attn_W, dec_Wih,
                                        dec_bhh, attn_v, enc_proj_b, enc_out_b,
                                        hbuf, gh_ws, hW_ws, ctx_ws, dec_out_b, bar);

  // logits = dec_out @ fc_W^T + fc_b  (M=4096, N=16000, K=512) -> fp32 out
  gemm_bt<float><<<dim3(125, 32), 256, 0, stream>>>(dec_out_b, 512, fcW_b, 512,
                                                    out, VTsz, fc_b, 512);
}